// Round 6
// baseline (173056.006 us; speedup 1.0000x reference)
//
#include <hip/hip_runtime.h>

#define GWG 256      // workgroups (1 per CU)
#define BTH 768      // threads per WG (12 waves)
#define WROW 2052    // LDS row pitch for Wih1 (bf16 elems): 2048 + 4 (bank de-alias)
#define LDSZ 137664
#define TB   0x5AB00001   // tag base: step t posts tag TB+t

typedef float f4v __attribute__((ext_vector_type(4)));

// ---------- helpers ----------
__device__ __forceinline__ unsigned short b16(float f) {   // f32 -> bf16 (RNE)
  union { float f; unsigned int i; } z; z.f = f;
  unsigned int r = z.i + 0x7fffu + ((z.i >> 16) & 1u);
  return (unsigned short)(r >> 16);
}
__device__ __forceinline__ float bup(unsigned short u) {
  union { unsigned int i; float f; } z; z.i = ((unsigned int)u) << 16; return z.f;
}
__device__ __forceinline__ float blo(unsigned int p) {
  union { unsigned int i; float f; } z; z.i = p << 16; return z.f;
}
__device__ __forceinline__ float bhi(unsigned int p) {
  union { unsigned int i; float f; } z; z.i = p & 0xffff0000u; return z.f;
}
__device__ __forceinline__ float sigm(float x) { return 1.f / (1.f + expf(-x)); }

__device__ __forceinline__ void cohSi(int* p, int v) {
  __hip_atomic_store(p, v, __ATOMIC_RELAXED, __HIP_MEMORY_SCOPE_AGENT);
}

// global (CP-scope) tagged-chunk ops — proven path (R5)
__device__ __forceinline__ f4v pollG(const float* gp, int tag) {
  f4v v;
  for (;;) {
    asm volatile("global_load_dwordx4 %0, %1, off sc0 sc1\n\ts_waitcnt vmcnt(0)"
                 : "=v"(v) : "v"(gp) : "memory");
    if (__float_as_int(v[3]) == tag) return v;
    __builtin_amdgcn_s_sleep(1);
  }
}
__device__ __forceinline__ void stG(float* p2, f4v v) {
  asm volatile("global_store_dwordx4 %0, %1, off sc0 sc1" :: "v"(p2), "v"(v) : "memory");
}
// XCD-local (L2-scope) mirror ops; poll falls back to global after 128 spins
__device__ __forceinline__ void stL(float* p2, f4v v) {
  asm volatile("global_store_dwordx4 %0, %1, off sc0" :: "v"(p2), "v"(v) : "memory");
}
__device__ __forceinline__ f4v pollL(const float* lp, const float* gp, int tag) {
  f4v v;
  for (int s = 0; s < 128; ++s) {
    asm volatile("global_load_dwordx4 %0, %1, off sc0\n\ts_waitcnt vmcnt(0)"
                 : "=v"(v) : "v"(lp) : "memory");
    if (__float_as_int(v[3]) == tag) return v;
    __builtin_amdgcn_s_sleep(1);
  }
  return pollG(gp, tag);
}

// ---------- pre-kernels ----------
__global__ __launch_bounds__(256) void prep(const float* __restrict__ bih0, const float* __restrict__ bhh0,
                                            const float* __restrict__ bih1, const float* __restrict__ bhh1,
                                            float* __restrict__ b0, float* __restrict__ b1f) {
  int i = blockIdx.x * 256 + threadIdx.x;
  if (i < 8192) { b0[i] = bih0[i] + bhh0[i]; b1f[i] = bih1[i] + bhh1[i]; }
}

__global__ __launch_bounds__(256) void transpose_wx(const float* __restrict__ Wih0, float* __restrict__ WxT) {
  int idx = blockIdx.x * 256 + threadIdx.x;          // 360*8192 total
  int r = idx & 8191, k = idx >> 13;
  WxT[(size_t)k * 8192 + r] = Wih0[(size_t)r * 424 + k];
}

// gates_x = inputVecs @ Wx^T + b0, stored bf16, only gate rows {i,g,o}
__global__ __launch_bounds__(256) void gemm_gx(const float* __restrict__ inV, const float* __restrict__ WxT,
                                               const float* __restrict__ b0, unsigned short* __restrict__ gxb) {
  __shared__ float lin[32 * 360];
  int t0 = blockIdx.x * 32;
  int by = blockIdx.y;                 // 0..23
  int ry = by >> 3;
  int gatey = ry + (ry ? 1 : 0);       // {0,2,3}
  int r = gatey * 2048 + (by & 7) * 256 + threadIdx.x;
  for (int i = threadIdx.x; i < 32 * 360; i += 256) lin[i] = inV[(size_t)t0 * 360 + i];
  __syncthreads();
  float b = b0[r];
  float acc[32];
#pragma unroll
  for (int tt = 0; tt < 32; ++tt) acc[tt] = b;
  for (int k = 0; k < 360; k += 4) {
    float w0 = WxT[(size_t)(k + 0) * 8192 + r];
    float w1 = WxT[(size_t)(k + 1) * 8192 + r];
    float w2 = WxT[(size_t)(k + 2) * 8192 + r];
    float w3 = WxT[(size_t)(k + 3) * 8192 + r];
#pragma unroll
    for (int tt = 0; tt < 32; ++tt) {
      float4 l = *reinterpret_cast<const float4*>(&lin[tt * 360 + k]);
      acc[tt] = fmaf(w0, l.x, fmaf(w1, l.y, fmaf(w2, l.z, fmaf(w3, l.w, acc[tt]))));
    }
  }
  for (int tt = 0; tt < 32; ++tt) gxb[(size_t)(t0 + tt) * 8192 + r] = b16(acc[tt]);
}

// Wcomb = We @ Wmap, compact igo rows [6144][512], bf16
__global__ __launch_bounds__(256) void wcomb_k(const float* __restrict__ Wih0, const float* __restrict__ Wmap,
                                               unsigned short* __restrict__ wcomb) {
  __shared__ float lwe[64];
  int cr = blockIdx.x;                               // compact row 0..6143
  int orig = cr + (cr >= 2048 ? 2048 : 0);           // gate {0,2,3}
  if (threadIdx.x < 64) lwe[threadIdx.x] = Wih0[(size_t)orig * 424 + 360 + threadIdx.x];
  __syncthreads();
  int c = threadIdx.x;
  float a0 = 0.f, a1 = 0.f;
  for (int e = 0; e < 64; ++e) {
    float w = lwe[e];
    a0 = fmaf(w, Wmap[e * 512 + c], a0);
    a1 = fmaf(w, Wmap[e * 512 + c + 256], a1);
  }
  wcomb[(size_t)cr * 512 + c] = b16(a0);
  wcomb[(size_t)cr * 512 + c + 256] = b16(a1);
}

// rs = rowsum(Wcomb_bf16); bcomb = We@bmap; g0c = We@embed0; reset xcd counters
__global__ __launch_bounds__(256) void rsk(const unsigned short* __restrict__ wcomb,
                                           const float* __restrict__ Wih0,
                                           const float* __restrict__ bmap, const float* __restrict__ emb0,
                                           float* __restrict__ rs, float* __restrict__ bcomb,
                                           float* __restrict__ g0c, int* xcdcnt) {
  if (blockIdx.x == 0 && threadIdx.x < 8) cohSi(&xcdcnt[threadIdx.x * 16], 0);
  int cr = blockIdx.x * 256 + threadIdx.x;
  if (cr >= 6144) return;
  int orig = cr + (cr >= 2048 ? 2048 : 0);
  float s = 0.f;
  for (int k = 0; k < 512; ++k) s += bup(wcomb[(size_t)cr * 512 + k]);
  float bc = 0.f, g0 = 0.f;
  for (int e = 0; e < 64; ++e) {
    float w = Wih0[(size_t)orig * 424 + 360 + e];
    bc = fmaf(w, bmap[e], bc);
    g0 = fmaf(w, emb0[e], g0);
  }
  rs[cr] = s; bcomb[cr] = bc; g0c[cr] = g0;
}

// ---------- persistent scan kernel ----------
struct KP {
  const float* Wih1; const float* Wlin; const float* blin; const float* b1f;
  const unsigned short* gxb; const unsigned short* wcomb;
  const float* rs; const float* bcomb; const float* g0c;
  float* mb_h0; float* mb_h1; float* mb_y;     // global tagged mailboxes
  float* mir;                                   // 8 XCDs x 8192 floats (local mirrors)
  int* xcdcnt;
  float* out;
};

__global__ __launch_bounds__(BTH) void lstm_seq(KP p) {
  extern __shared__ __align__(16) char smem[];
  unsigned short* lW1  = (unsigned short*)smem;                 // 24 x WROW (Wih1 slice)  98,496
  unsigned short* lWcb = (unsigned short*)(smem + 98496);       // 24 x 512  (Wcomb slice) 24,576
  unsigned short* lWl  = (unsigned short*)(smem + 123072);      // 2 x 2048  (Wlin rows)    8,192
  unsigned short* lHb  = (unsigned short*)(smem + 131264);      // 2048 bf16 (h gather)     4,096
  float* lY = (float*)(smem + 135360);                          // 512
  float* lR = (float*)(smem + 137408);                          // 24 (+pad)
  float* lV = (float*)(smem + 137536);                          // 8  (+pad)
  int* lMeta = (int*)(smem + 137600);

  const int w = blockIdx.x, tid = threadIdx.x;
  const int rl = tid >> 5;          // 0..23 gate-row
  const int l32 = tid & 31;
  const int g3 = rl >> 3;                   // 0,1,2 (i,g,o compact)
  const int gate = g3 + (g3 ? 1 : 0);       // {0,2,3} original layout
  const int gr  = w * 8 + (rl & 7) + 2048 * gate;
  const int crt = w * 8 + (rl & 7) + 2048 * g3;

  // ---- XCD identification + rank election ----
  int xcd;
  asm volatile("s_getreg_b32 %0, hwreg(HW_REG_XCC_ID)" : "=s"(xcd));
  xcd &= 7;
  if (tid == 0) {
    int r = __hip_atomic_fetch_add(&p.xcdcnt[xcd * 16], 1, __ATOMIC_RELAXED, __HIP_MEMORY_SCOPE_AGENT);
    lMeta[0] = r;
  }

  // ---- stage weights into LDS (once) ----
  for (int r2 = 0; r2 < 24; ++r2) {
    int gg = r2 >> 3; int grr = w * 8 + (r2 & 7) + 2048 * (gg + (gg ? 1 : 0));
    const float* src = p.Wih1 + (size_t)grr * 2048;
    for (int i = tid; i < 2048; i += BTH) lW1[r2 * WROW + i] = b16(src[i]);
  }
  for (int i = tid; i < 24 * 512; i += BTH) {
    int r2 = i >> 9, k = i & 511;
    int crr = w * 8 + (r2 & 7) + 2048 * (r2 >> 3);
    lWcb[r2 * 512 + k] = p.wcomb[(size_t)crr * 512 + k];
  }
  for (int i = tid; i < 2 * 2048; i += BTH) {
    int q = i >> 11, k = i & 2047;
    lWl[i] = b16(p.Wlin[(size_t)(w * 2 + q) * 2048 + k]);
  }
  const float b1r = p.b1f[gr];
  const float rs_r = p.rs[crt], bc_r = p.bcomb[crt], g0_r = p.g0c[crt];
  const float bl0 = p.blin[w * 2], bl1 = p.blin[w * 2 + 1];
  unsigned short gxu = p.gxb[gr];                  // gx for t=0
  __syncthreads();

  const int rank = lMeta[0];
  const bool relH0 = (rank == 0), relH1 = (rank == 1), relY = (rank == 2);
  float* mirB  = p.mir + (size_t)xcd * 8192;
  float* mirH0 = mirB;            // 512 chunks
  float* mirH1 = mirB + 2048;     // 512 chunks
  float* mirY  = mirB + 4096;     // 256 chunks

  for (int t = 0; t < 4096; ++t) {
    const int tagt = TB + t;
    const unsigned short gxu_n = p.gxb[(size_t)(t < 4095 ? t + 1 : t) * 8192 + gr];
    // ============ phase 1: gather y(t-1), lse, gates0 fold ============
    if (t > 0) {
      if (tid < 256) {
        const float* gp = p.mb_y + tid * 4;
        float* lp = mirY + tid * 4;
        f4v c;
        if (relY) { c = pollG(gp, tagt - 1); stL(lp, c); }
        else      { c = pollL(lp, gp, tagt - 1); }
        lY[2 * tid] = c[0]; lY[2 * tid + 1] = c[1];
      }
      __syncthreads();                                         // S1
      float s = 0.f;
      if (tid < 512) {
        s = expf(lY[tid]);
#pragma unroll
        for (int d = 1; d < 64; d <<= 1) s += __shfl_xor(s, d);
        if ((tid & 63) == 0) lV[tid >> 6] = s;
      }
      __syncthreads();                                         // S2
      float lse = logf(lV[0] + lV[1] + lV[2] + lV[3] + lV[4] + lV[5] + lV[6] + lV[7]);
      float acc = 0.f;
#pragma unroll
      for (int j = 0; j < 8; ++j) {
        int k = 2 * l32 + 64 * j;
        unsigned uwp = *(const unsigned*)&lWcb[rl * 512 + k];
        float2 yv2 = *(const float2*)&lY[k];
        acc = fmaf(blo(uwp), yv2.x, fmaf(bhi(uwp), yv2.y, acc));
      }
      acc += __shfl_xor(acc, 1); acc += __shfl_xor(acc, 2); acc += __shfl_xor(acc, 4);
      acc += __shfl_xor(acc, 8); acc += __shfl_xor(acc, 16);
      if (l32 == 0) lR[rl] = bup(gxu) + acc - lse * rs_r + bc_r;
    } else {
      if (l32 == 0) lR[rl] = bup(gxu) + g0_r;
    }
    __syncthreads();                                           // S3
    // wave0: cell -> h0, shuffle-pack, post (2 bf16x4 chunks)
    if (tid < 8) {
      float cc = sigm(lR[tid]) * tanhf(lR[8 + tid]);
      float h  = sigm(lR[16 + tid]) * tanhf(cc);
      unsigned hb = (unsigned)b16(h);
      unsigned a0 = __shfl(hb, tid * 4 + 0);
      unsigned a1 = __shfl(hb, tid * 4 + 1);
      unsigned a2 = __shfl(hb, tid * 4 + 2);
      unsigned a3 = __shfl(hb, tid * 4 + 3);
      if (tid < 2) {
        f4v c;
        c[0] = __uint_as_float(a0 | (a1 << 16));
        c[1] = __uint_as_float(a2 | (a3 << 16));
        c[2] = 0.f; c[3] = __int_as_float(tagt);
        stG(p.mb_h0 + w * 8 + tid * 4, c);
      }
    }
    // ============ phase 2: gather h0 (two-level), h1 matvec ============
    if (tid < 512) {
      const float* gp = p.mb_h0 + (tid >> 1) * 8 + (tid & 1) * 4;
      float* lp = mirH0 + tid * 4;
      f4v c;
      if (relH0) { c = pollG(gp, tagt); stL(lp, c); }
      else       { c = pollL(lp, gp, tagt); }
      uint2 u; u.x = __float_as_uint(c[0]); u.y = __float_as_uint(c[1]);
      *(uint2*)&lHb[tid * 4] = u;
    }
    __syncthreads();                                           // S5
    {
      float acc = 0.f;
      const unsigned short* wr = lW1 + rl * WROW;
#pragma unroll 4
      for (int mm = 0; mm < 16; ++mm) {
        int k = l32 * 4 + mm * 128;
        ushort4 uw = *(const ushort4*)&wr[k];
        ushort4 uh = *(const ushort4*)&lHb[k];
        acc = fmaf(bup(uw.x), bup(uh.x), acc);
        acc = fmaf(bup(uw.y), bup(uh.y), acc);
        acc = fmaf(bup(uw.z), bup(uh.z), acc);
        acc = fmaf(bup(uw.w), bup(uh.w), acc);
      }
      acc += __shfl_xor(acc, 1); acc += __shfl_xor(acc, 2); acc += __shfl_xor(acc, 4);
      acc += __shfl_xor(acc, 8); acc += __shfl_xor(acc, 16);
      if (l32 == 0) lR[rl] = acc + b1r;
    }
    __syncthreads();                                           // S6
    // wave0: cell -> h1, post
    if (tid < 8) {
      float cc = sigm(lR[tid]) * tanhf(lR[8 + tid]);
      float h  = sigm(lR[16 + tid]) * tanhf(cc);
      unsigned hb = (unsigned)b16(h);
      unsigned a0 = __shfl(hb, tid * 4 + 0);
      unsigned a1 = __shfl(hb, tid * 4 + 1);
      unsigned a2 = __shfl(hb, tid * 4 + 2);
      unsigned a3 = __shfl(hb, tid * 4 + 3);
      if (tid < 2) {
        f4v c;
        c[0] = __uint_as_float(a0 | (a1 << 16));
        c[1] = __uint_as_float(a2 | (a3 << 16));
        c[2] = 0.f; c[3] = __int_as_float(tagt);
        stG(p.mb_h1 + w * 8 + tid * 4, c);
      }
    }
    // ============ phase 3: gather h1 (two-level), y rows, post y ============
    if (tid < 512) {
      const float* gp = p.mb_h1 + (tid >> 1) * 8 + (tid & 1) * 4;
      float* lp = mirH1 + tid * 4;
      f4v c;
      if (relH1) { c = pollG(gp, tagt); stL(lp, c); }
      else       { c = pollL(lp, gp, tagt); }
      uint2 u; u.x = __float_as_uint(c[0]); u.y = __float_as_uint(c[1]);
      *(uint2*)&lHb[tid * 4] = u;
    }
    __syncthreads();                                           // S8
    if (tid < 512) {
      int q = tid >> 8, l = tid & 255;
      float a = 0.f;
#pragma unroll
      for (int it = 0; it < 2; ++it) {
        int k = it * 1024 + l * 4;
        ushort4 uw = *(const ushort4*)&lWl[q * 2048 + k];
        ushort4 uh = *(const ushort4*)&lHb[k];
        a = fmaf(bup(uw.x), bup(uh.x), a);
        a = fmaf(bup(uw.y), bup(uh.y), a);
        a = fmaf(bup(uw.z), bup(uh.z), a);
        a = fmaf(bup(uw.w), bup(uh.w), a);
      }
#pragma unroll
      for (int d = 1; d < 64; d <<= 1) a += __shfl_xor(a, d);
      if ((tid & 63) == 0) lV[tid >> 6] = a;
    }
    __syncthreads();                                           // S9
    if (tid == 0) {
      float y0 = lV[0] + lV[1] + lV[2] + lV[3] + bl0;
      float y1 = lV[4] + lV[5] + lV[6] + lV[7] + bl1;
      f4v c; c[0] = y0; c[1] = y1; c[2] = 0.f; c[3] = __int_as_float(tagt);
      stG(p.mb_y + w * 4, c);
      p.out[(size_t)t * 512 + w * 2]     = y0;
      p.out[(size_t)t * 512 + w * 2 + 1] = y1;
    }
    gxu = gxu_n;
  }
}

// ---------- host ----------
extern "C" void kernel_launch(void* const* d_in, const int* in_sizes, int n_in,
                              void* d_out, int out_size, void* d_ws, size_t ws_size,
                              hipStream_t stream) {
  const float* inV  = (const float*)d_in[0];
  const float* Wih0 = (const float*)d_in[1];
  const float* bih0 = (const float*)d_in[2];
  const float* bhh0 = (const float*)d_in[3];
  const float* Wih1 = (const float*)d_in[4];
  const float* bih1 = (const float*)d_in[5];
  const float* bhh1 = (const float*)d_in[6];
  const float* Wlin = (const float*)d_in[7];
  const float* blin = (const float*)d_in[8];
  const float* Wmap = (const float*)d_in[9];
  const float* bmap = (const float*)d_in[10];
  const float* emb0 = (const float*)d_in[11];

  char* ws = (char*)d_ws;
  unsigned short* gxb   = (unsigned short*)(ws);             // 67,108,864 B
  float*          WxT   = (float*)(ws + 67108864);           // 11,796,480 B (dead after gemm_gx)
  unsigned short* wcomb = (unsigned short*)(ws + 67108864);  // 6,291,456 B (aliases WxT)
  int*   xcdcnt = (int*)  (ws + 73400320);                   // 512 B (reset in rsk, after WxT writes)
  float* mir    = (float*)(ws + 73400832);                   // 8 x 32 KB local mirrors
  float* b0     = (float*)(ws + 78905344);
  float* b1f    = (float*)(ws + 78938112);
  float* mb_h0  = (float*)(ws + 78970880);                   // 8 KB (256 x 2 chunks)
  float* mb_h1  = (float*)(ws + 78979072);                   // 8 KB
  float* mb_y   = (float*)(ws + 78987264);                   // 4 KB
  float* rs     = (float*)(ws + 78991360);                   // 24 KB
  float* bcomb  = (float*)(ws + 79015936);                   // 24 KB
  float* g0c    = (float*)(ws + 79040512);                   // 24 KB
  float* out    = (float*)d_out;

  prep<<<32, 256, 0, stream>>>(bih0, bhh0, bih1, bhh1, b0, b1f);
  transpose_wx<<<11520, 256, 0, stream>>>(Wih0, WxT);
  gemm_gx<<<dim3(128, 24), 256, 0, stream>>>(inV, WxT, b0, gxb);
  wcomb_k<<<6144, 256, 0, stream>>>(Wih0, Wmap, wcomb);      // overwrites WxT region (now dead)
  rsk<<<24, 256, 0, stream>>>(wcomb, Wih0, bmap, emb0, rs, bcomb, g0c, xcdcnt);

  hipFuncSetAttribute(reinterpret_cast<const void*>(lstm_seq),
                      hipFuncAttributeMaxDynamicSharedMemorySize, LDSZ);
  KP p{Wih1, Wlin, blin, b1f, gxb, wcomb, rs, bcomb, g0c, mb_h0, mb_h1, mb_y, mir, xcdcnt, out};
  void* args[] = { (void*)&p };
  hipError_t e = hipLaunchCooperativeKernel(reinterpret_cast<void*>(&lstm_seq),
                                            dim3(GWG), dim3(BTH), args, LDSZ, stream);
  if (e != hipSuccess) {
    lstm_seq<<<GWG, BTH, LDSZ, stream>>>(p);
  }
}

// Round 7
// 31463.260 us; speedup vs baseline: 5.5003x; 5.5003x over previous
//
#include <hip/hip_runtime.h>

#define GWG 256      // workgroups (1 per CU)
#define BTH 768      // threads per WG (12 waves)
#define WROW 2052    // LDS row pitch for Wih1 (bf16 elems): 2048 + 4 (bank de-alias)
#define LDSZ 137600
#define TB   0x5AB00001   // tag base: step t posts tag TB+t

typedef float f4v __attribute__((ext_vector_type(4)));

// ---------- helpers ----------
__device__ __forceinline__ unsigned short b16(float f) {   // f32 -> bf16 (RNE)
  union { float f; unsigned int i; } z; z.f = f;
  unsigned int r = z.i + 0x7fffu + ((z.i >> 16) & 1u);
  return (unsigned short)(r >> 16);
}
__device__ __forceinline__ float bup(unsigned short u) {
  union { unsigned int i; float f; } z; z.i = ((unsigned int)u) << 16; return z.f;
}
__device__ __forceinline__ float blo(unsigned int p) {
  union { unsigned int i; float f; } z; z.i = p << 16; return z.f;
}
__device__ __forceinline__ float bhi(unsigned int p) {
  union { unsigned int i; float f; } z; z.i = p & 0xffff0000u; return z.f;
}
__device__ __forceinline__ float sigm(float x) { return 1.f / (1.f + expf(-x)); }

__device__ __forceinline__ void stG(float* p2, f4v v) {
  asm volatile("global_store_dwordx4 %0, %1, off sc0 sc1" :: "v"(p2), "v"(v) : "memory");
}

// wave-0 batched gather: 64 lanes x 8 chunks (stride 64 chunks), bf16 payload -> LDS
__device__ __forceinline__ void pollH(const float* mb, int tag, unsigned short* lHb) {
  const int L = threadIdx.x;                 // caller guarantees < 64
  const float* base = mb + L * 4;
  f4v v[8];
  for (;;) {
#pragma unroll
    for (int s = 0; s < 8; ++s)
      asm volatile("global_load_dwordx4 %0, %1, off sc0 sc1"
                   : "=v"(v[s]) : "v"(base + s * 256) : "memory");
    asm volatile("s_waitcnt vmcnt(0)" ::: "memory");
    __builtin_amdgcn_sched_barrier(0);
    bool ok = true;
#pragma unroll
    for (int s = 0; s < 8; ++s) ok &= (__float_as_int(v[s][3]) == tag);
    if (__all(ok)) break;
    __builtin_amdgcn_s_sleep(1);
  }
#pragma unroll
  for (int s = 0; s < 8; ++s) {
    int c = s * 64 + L;
    uint2 u; u.x = __float_as_uint(v[s][0]); u.y = __float_as_uint(v[s][1]);
    *(uint2*)&lHb[c * 4] = u;                // 4 bf16 = 8B per chunk
  }
}
// wave-0 batched y gather: 64 lanes x 4 chunks (2 f32 payload)
__device__ __forceinline__ void pollY(const float* mb, int tag, float* lY) {
  const int L = threadIdx.x;
  const float* base = mb + L * 4;
  f4v v[4];
  for (;;) {
#pragma unroll
    for (int s = 0; s < 4; ++s)
      asm volatile("global_load_dwordx4 %0, %1, off sc0 sc1"
                   : "=v"(v[s]) : "v"(base + s * 256) : "memory");
    asm volatile("s_waitcnt vmcnt(0)" ::: "memory");
    __builtin_amdgcn_sched_barrier(0);
    bool ok = true;
#pragma unroll
    for (int s = 0; s < 4; ++s) ok &= (__float_as_int(v[s][3]) == tag);
    if (__all(ok)) break;
    __builtin_amdgcn_s_sleep(1);
  }
#pragma unroll
  for (int s = 0; s < 4; ++s) {
    int c = s * 64 + L;
    lY[c * 2] = v[s][0]; lY[c * 2 + 1] = v[s][1];
  }
}

// ---------- pre-kernels ----------
__global__ __launch_bounds__(256) void prep(const float* __restrict__ bih0, const float* __restrict__ bhh0,
                                            const float* __restrict__ bih1, const float* __restrict__ bhh1,
                                            float* __restrict__ b0, float* __restrict__ b1f) {
  int i = blockIdx.x * 256 + threadIdx.x;
  if (i < 8192) { b0[i] = bih0[i] + bhh0[i]; b1f[i] = bih1[i] + bhh1[i]; }
}

__global__ __launch_bounds__(256) void transpose_wx(const float* __restrict__ Wih0, float* __restrict__ WxT) {
  int idx = blockIdx.x * 256 + threadIdx.x;          // 360*8192 total
  int r = idx & 8191, k = idx >> 13;
  WxT[(size_t)k * 8192 + r] = Wih0[(size_t)r * 424 + k];
}

// gates_x = inputVecs @ Wx^T + b0, stored bf16, only gate rows {i,g,o}
__global__ __launch_bounds__(256) void gemm_gx(const float* __restrict__ inV, const float* __restrict__ WxT,
                                               const float* __restrict__ b0, unsigned short* __restrict__ gxb) {
  __shared__ float lin[32 * 360];
  int t0 = blockIdx.x * 32;
  int by = blockIdx.y;                 // 0..23
  int ry = by >> 3;
  int gatey = ry + (ry ? 1 : 0);       // {0,2,3}
  int r = gatey * 2048 + (by & 7) * 256 + threadIdx.x;
  for (int i = threadIdx.x; i < 32 * 360; i += 256) lin[i] = inV[(size_t)t0 * 360 + i];
  __syncthreads();
  float b = b0[r];
  float acc[32];
#pragma unroll
  for (int tt = 0; tt < 32; ++tt) acc[tt] = b;
  for (int k = 0; k < 360; k += 4) {
    float w0 = WxT[(size_t)(k + 0) * 8192 + r];
    float w1 = WxT[(size_t)(k + 1) * 8192 + r];
    float w2 = WxT[(size_t)(k + 2) * 8192 + r];
    float w3 = WxT[(size_t)(k + 3) * 8192 + r];
#pragma unroll
    for (int tt = 0; tt < 32; ++tt) {
      float4 l = *reinterpret_cast<const float4*>(&lin[tt * 360 + k]);
      acc[tt] = fmaf(w0, l.x, fmaf(w1, l.y, fmaf(w2, l.z, fmaf(w3, l.w, acc[tt]))));
    }
  }
  for (int tt = 0; tt < 32; ++tt) gxb[(size_t)(t0 + tt) * 8192 + r] = b16(acc[tt]);
}

// Wcomb = We @ Wmap, compact igo rows [6144][512], bf16
__global__ __launch_bounds__(256) void wcomb_k(const float* __restrict__ Wih0, const float* __restrict__ Wmap,
                                               unsigned short* __restrict__ wcomb) {
  __shared__ float lwe[64];
  int cr = blockIdx.x;                               // compact row 0..6143
  int orig = cr + (cr >= 2048 ? 2048 : 0);           // gate {0,2,3}
  if (threadIdx.x < 64) lwe[threadIdx.x] = Wih0[(size_t)orig * 424 + 360 + threadIdx.x];
  __syncthreads();
  int c = threadIdx.x;
  float a0 = 0.f, a1 = 0.f;
  for (int e = 0; e < 64; ++e) {
    float w = lwe[e];
    a0 = fmaf(w, Wmap[e * 512 + c], a0);
    a1 = fmaf(w, Wmap[e * 512 + c + 256], a1);
  }
  wcomb[(size_t)cr * 512 + c] = b16(a0);
  wcomb[(size_t)cr * 512 + c + 256] = b16(a1);
}

// rs = rowsum(Wcomb_bf16); bcomb = We@bmap; g0c = We@embed0
__global__ __launch_bounds__(256) void rsk(const unsigned short* __restrict__ wcomb,
                                           const float* __restrict__ Wih0,
                                           const float* __restrict__ bmap, const float* __restrict__ emb0,
                                           float* __restrict__ rs, float* __restrict__ bcomb,
                                           float* __restrict__ g0c) {
  int cr = blockIdx.x * 256 + threadIdx.x;
  if (cr >= 6144) return;
  int orig = cr + (cr >= 2048 ? 2048 : 0);
  float s = 0.f;
  for (int k = 0; k < 512; ++k) s += bup(wcomb[(size_t)cr * 512 + k]);
  float bc = 0.f, g0 = 0.f;
  for (int e = 0; e < 64; ++e) {
    float w = Wih0[(size_t)orig * 424 + 360 + e];
    bc = fmaf(w, bmap[e], bc);
    g0 = fmaf(w, emb0[e], g0);
  }
  rs[cr] = s; bcomb[cr] = bc; g0c[cr] = g0;
}

// ---------- persistent scan kernel ----------
struct KP {
  const float* Wih1; const float* Wlin; const float* blin; const float* b1f;
  const unsigned short* gxb; const unsigned short* wcomb;
  const float* rs; const float* bcomb; const float* g0c;
  float* mb_h0; float* mb_h1; float* mb_y;     // global tagged mailboxes
  float* out;
};

__global__ __launch_bounds__(BTH) void lstm_seq(KP p) {
  extern __shared__ __align__(16) char smem[];
  unsigned short* lW1  = (unsigned short*)smem;                 // 24 x WROW (Wih1 slice)  98,496
  unsigned short* lWcb = (unsigned short*)(smem + 98496);       // 24 x 512  (Wcomb slice) 24,576
  unsigned short* lWl  = (unsigned short*)(smem + 123072);      // 2 x 2048  (Wlin rows)    8,192
  unsigned short* lHb  = (unsigned short*)(smem + 131264);      // 2048 bf16 (h gather)     4,096
  float* lY = (float*)(smem + 135360);                          // 512
  float* lR = (float*)(smem + 137408);                          // 24 (+pad)
  float* lV = (float*)(smem + 137504);                          // 8  (+pad)

  const int w = blockIdx.x, tid = threadIdx.x;
  const int rl = tid >> 5;          // 0..23 gate-row
  const int l32 = tid & 31;
  const int g3 = rl >> 3;                   // 0,1,2 (i,g,o compact)
  const int gate = g3 + (g3 ? 1 : 0);       // {0,2,3} original layout
  const int gr  = w * 8 + (rl & 7) + 2048 * gate;
  const int crt = w * 8 + (rl & 7) + 2048 * g3;

  // ---- stage weights into LDS (once) ----
  for (int r2 = 0; r2 < 24; ++r2) {
    int gg = r2 >> 3; int grr = w * 8 + (r2 & 7) + 2048 * (gg + (gg ? 1 : 0));
    const float* src = p.Wih1 + (size_t)grr * 2048;
    for (int i = tid; i < 2048; i += BTH) lW1[r2 * WROW + i] = b16(src[i]);
  }
  for (int i = tid; i < 24 * 512; i += BTH) {
    int r2 = i >> 9, k = i & 511;
    int crr = w * 8 + (r2 & 7) + 2048 * (r2 >> 3);
    lWcb[r2 * 512 + k] = p.wcomb[(size_t)crr * 512 + k];
  }
  for (int i = tid; i < 2 * 2048; i += BTH) {
    int q = i >> 11, k = i & 2047;
    lWl[i] = b16(p.Wlin[(size_t)(w * 2 + q) * 2048 + k]);
  }
  const float b1r = p.b1f[gr];
  const float rs_r = p.rs[crt], bc_r = p.bcomb[crt], g0_r = p.g0c[crt];
  const float bl0 = p.blin[w * 2], bl1 = p.blin[w * 2 + 1];
  unsigned short gxu = p.gxb[gr];                  // gx for t=0
  __syncthreads();

  for (int t = 0; t < 4096; ++t) {
    const int tagt = TB + t;
    const unsigned short gxu_n = p.gxb[(size_t)(t < 4095 ? t + 1 : t) * 8192 + gr];
    // ============ phase 1: gather y(t-1) [wave0], lse, gates0 fold ============
    if (t > 0) {
      if (tid < 64) pollY(p.mb_y, tagt - 1, lY);
      __syncthreads();                                         // S1
      float s = 0.f;
      if (tid < 512) {
        s = expf(lY[tid]);
#pragma unroll
        for (int d = 1; d < 64; d <<= 1) s += __shfl_xor(s, d);
        if ((tid & 63) == 0) lV[tid >> 6] = s;
      }
      __syncthreads();                                         // S2
      float lse = logf(lV[0] + lV[1] + lV[2] + lV[3] + lV[4] + lV[5] + lV[6] + lV[7]);
      float acc = 0.f;
#pragma unroll
      for (int j = 0; j < 8; ++j) {
        int k = 2 * l32 + 64 * j;
        unsigned uwp = *(const unsigned*)&lWcb[rl * 512 + k];
        float2 yv2 = *(const float2*)&lY[k];
        acc = fmaf(blo(uwp), yv2.x, fmaf(bhi(uwp), yv2.y, acc));
      }
      acc += __shfl_xor(acc, 1); acc += __shfl_xor(acc, 2); acc += __shfl_xor(acc, 4);
      acc += __shfl_xor(acc, 8); acc += __shfl_xor(acc, 16);
      if (l32 == 0) lR[rl] = bup(gxu) + acc - lse * rs_r + bc_r;
    } else {
      if (l32 == 0) lR[rl] = bup(gxu) + g0_r;
    }
    __syncthreads();                                           // S3
    // wave0: cell -> h0, shuffle-pack, post (2 bf16x4 tagged chunks)
    if (tid < 8) {
      float cc = sigm(lR[tid]) * tanhf(lR[8 + tid]);
      float h  = sigm(lR[16 + tid]) * tanhf(cc);
      unsigned hb = (unsigned)b16(h);
      unsigned a0 = __shfl(hb, tid * 4 + 0);
      unsigned a1 = __shfl(hb, tid * 4 + 1);
      unsigned a2 = __shfl(hb, tid * 4 + 2);
      unsigned a3 = __shfl(hb, tid * 4 + 3);
      if (tid < 2) {
        f4v c;
        c[0] = __uint_as_float(a0 | (a1 << 16));
        c[1] = __uint_as_float(a2 | (a3 << 16));
        c[2] = 0.f; c[3] = __int_as_float(tagt);
        stG(p.mb_h0 + w * 8 + tid * 4, c);
      }
    }
    // ============ phase 2: gather h0 [wave0], h1 matvec ============
    if (tid < 64) pollH(p.mb_h0, tagt, lHb);
    __syncthreads();                                           // S5
    {
      float acc = 0.f;
      const unsigned short* wr = lW1 + rl * WROW;
#pragma unroll 4
      for (int mm = 0; mm < 16; ++mm) {
        int k = l32 * 4 + mm * 128;
        ushort4 uw = *(const ushort4*)&wr[k];
        ushort4 uh = *(const ushort4*)&lHb[k];
        acc = fmaf(bup(uw.x), bup(uh.x), acc);
        acc = fmaf(bup(uw.y), bup(uh.y), acc);
        acc = fmaf(bup(uw.z), bup(uh.z), acc);
        acc = fmaf(bup(uw.w), bup(uh.w), acc);
      }
      acc += __shfl_xor(acc, 1); acc += __shfl_xor(acc, 2); acc += __shfl_xor(acc, 4);
      acc += __shfl_xor(acc, 8); acc += __shfl_xor(acc, 16);
      if (l32 == 0) lR[rl] = acc + b1r;
    }
    __syncthreads();                                           // S6
    // wave0: cell -> h1, post
    if (tid < 8) {
      float cc = sigm(lR[tid]) * tanhf(lR[8 + tid]);
      float h  = sigm(lR[16 + tid]) * tanhf(cc);
      unsigned hb = (unsigned)b16(h);
      unsigned a0 = __shfl(hb, tid * 4 + 0);
      unsigned a1 = __shfl(hb, tid * 4 + 1);
      unsigned a2 = __shfl(hb, tid * 4 + 2);
      unsigned a3 = __shfl(hb, tid * 4 + 3);
      if (tid < 2) {
        f4v c;
        c[0] = __uint_as_float(a0 | (a1 << 16));
        c[1] = __uint_as_float(a2 | (a3 << 16));
        c[2] = 0.f; c[3] = __int_as_float(tagt);
        stG(p.mb_h1 + w * 8 + tid * 4, c);
      }
    }
    // ============ phase 3: gather h1 [wave0], y rows, post y ============
    if (tid < 64) pollH(p.mb_h1, tagt, lHb);
    __syncthreads();                                           // S8
    if (tid < 512) {
      int q = tid >> 8, l = tid & 255;
      float a = 0.f;
#pragma unroll
      for (int it = 0; it < 2; ++it) {
        int k = it * 1024 + l * 4;
        ushort4 uw = *(const ushort4*)&lWl[q * 2048 + k];
        ushort4 uh = *(const ushort4*)&lHb[k];
        a = fmaf(bup(uw.x), bup(uh.x), a);
        a = fmaf(bup(uw.y), bup(uh.y), a);
        a = fmaf(bup(uw.z), bup(uh.z), a);
        a = fmaf(bup(uw.w), bup(uh.w), a);
      }
#pragma unroll
      for (int d = 1; d < 64; d <<= 1) a += __shfl_xor(a, d);
      if ((tid & 63) == 0) lV[tid >> 6] = a;
    }
    __syncthreads();                                           // S9
    if (tid == 0) {
      float y0 = lV[0] + lV[1] + lV[2] + lV[3] + bl0;
      float y1 = lV[4] + lV[5] + lV[6] + lV[7] + bl1;
      f4v c; c[0] = y0; c[1] = y1; c[2] = 0.f; c[3] = __int_as_float(tagt);
      stG(p.mb_y + w * 4, c);
      p.out[(size_t)t * 512 + w * 2]     = y0;
      p.out[(size_t)t * 512 + w * 2 + 1] = y1;
    }
    gxu = gxu_n;
  }
}

// ---------- host ----------
extern "C" void kernel_launch(void* const* d_in, const int* in_sizes, int n_in,
                              void* d_out, int out_size, void* d_ws, size_t ws_size,
                              hipStream_t stream) {
  const float* inV  = (const float*)d_in[0];
  const float* Wih0 = (const float*)d_in[1];
  const float* bih0 = (const float*)d_in[2];
  const float* bhh0 = (const float*)d_in[3];
  const float* Wih1 = (const float*)d_in[4];
  const float* bih1 = (const float*)d_in[5];
  const float* bhh1 = (const float*)d_in[6];
  const float* Wlin = (const float*)d_in[7];
  const float* blin = (const float*)d_in[8];
  const float* Wmap = (const float*)d_in[9];
  const float* bmap = (const float*)d_in[10];
  const float* emb0 = (const float*)d_in[11];

  char* ws = (char*)d_ws;
  unsigned short* gxb   = (unsigned short*)(ws);             // 67,108,864 B
  float*          WxT   = (float*)(ws + 67108864);           // 11,796,480 B (dead after gemm_gx)
  unsigned short* wcomb = (unsigned short*)(ws + 67108864);  // 6,291,456 B (aliases WxT)
  float* b0     = (float*)(ws + 78905344);
  float* b1f    = (float*)(ws + 78938112);
  float* mb_h0  = (float*)(ws + 78970880);                   // 8 KB (512 x 16B)
  float* mb_h1  = (float*)(ws + 78979072);                   // 8 KB
  float* mb_y   = (float*)(ws + 78987264);                   // 4 KB (256 x 16B)
  float* rs     = (float*)(ws + 78991360);                   // 24 KB
  float* bcomb  = (float*)(ws + 79015936);                   // 24 KB
  float* g0c    = (float*)(ws + 79040512);                   // 24 KB
  float* out    = (float*)d_out;

  prep<<<32, 256, 0, stream>>>(bih0, bhh0, bih1, bhh1, b0, b1f);
  transpose_wx<<<11520, 256, 0, stream>>>(Wih0, WxT);
  gemm_gx<<<dim3(128, 24), 256, 0, stream>>>(inV, WxT, b0, gxb);
  wcomb_k<<<6144, 256, 0, stream>>>(Wih0, Wmap, wcomb);      // overwrites WxT region (now dead)
  rsk<<<24, 256, 0, stream>>>(wcomb, Wih0, bmap, emb0, rs, bcomb, g0c);

  hipFuncSetAttribute(reinterpret_cast<const void*>(lstm_seq),
                      hipFuncAttributeMaxDynamicSharedMemorySize, LDSZ);
  KP p{Wih1, Wlin, blin, b1f, gxb, wcomb, rs, bcomb, g0c, mb_h0, mb_h1, mb_y, out};
  void* args[] = { (void*)&p };
  hipError_t e = hipLaunchCooperativeKernel(reinterpret_cast<void*>(&lstm_seq),
                                            dim3(GWG), dim3(BTH), args, LDSZ, stream);
  if (e != hipSuccess) {
    lstm_seq<<<GWG, BTH, LDSZ, stream>>>(p);
  }
}